// Round 3
// baseline (253.465 us; speedup 1.0000x reference)
//
#include <hip/hip_runtime.h>
#include <hip/hip_bf16.h>
#include <stdint.h>

// Problem constants
#define M_REAL 36928LL      // 64*577
#define M_PAD  37120LL      // 145*256
#define DDIM   1024
#define SSEQ   577
#define NBATCH 64
#define NT     16           // K tiles (1024/64)

typedef __attribute__((ext_vector_type(8))) short bf16x8;
typedef __attribute__((ext_vector_type(4))) float f32x4;

// ws layout (bytes)
#define XBF_OFF   0ULL                  // 37120*1024*2 = 76,021,760
#define WBF_OFF   76021760ULL           // 1024*1024*2  =  2,097,152
#define ABF_OFF   78118912ULL           // 8*16*1024*2  =    262,144
#define XABF_OFF  78381056ULL           // 37120*32*2   =  2,375,680
#define GBBF_OFF  80756736ULL           // 64*1024*32*2 =  4,194,304
#define WS_NEED   84951040ULL

__device__ __forceinline__ unsigned short f2bf(float f) {
  union { float f; unsigned int u; } v; v.f = f;
  unsigned int u = v.u;
  unsigned int r = (u + 0x7fffu + ((u >> 16) & 1u)) >> 16;  // RNE
  return (unsigned short)r;
}

__device__ __forceinline__ bf16x8 cvt8(const float* __restrict__ p) {
  float4 a = *(const float4*)p;
  float4 b = *(const float4*)(p + 4);
  bf16x8 o;
  o[0] = (short)f2bf(a.x); o[1] = (short)f2bf(a.y);
  o[2] = (short)f2bf(a.z); o[3] = (short)f2bf(a.w);
  o[4] = (short)f2bf(b.x); o[5] = (short)f2bf(b.y);
  o[6] = (short)f2bf(b.z); o[7] = (short)f2bf(b.w);
  return o;
}

#define GLOAD_LDS16(gsrc, ldst)                                                  \
  __builtin_amdgcn_global_load_lds((const __attribute__((address_space(1))) void*)(gsrc), \
                                   (__attribute__((address_space(3))) void*)(ldst), 16, 0, 0)

// ---------------- kernel 1: cast x -> bf16, zero-pad rows to M_PAD ----------
__global__ void cast_x_kernel(const float* __restrict__ x,
                              unsigned short* __restrict__ xbf) {
  const long long NREAL = M_REAL * DDIM;
  const long long NTOT  = M_PAD * DDIM;
  long long t = (long long)blockIdx.x * blockDim.x + threadIdx.x;
  long long stride = (long long)gridDim.x * blockDim.x;
  for (long long i = t * 8; i < NTOT; i += stride * 8) {
    bf16x8 o;
    if (i < NREAL) {
      o = cvt8(x + i);
    } else {
#pragma unroll
      for (int j = 0; j < 8; ++j) o[j] = 0;
    }
    *(bf16x8*)(xbf + i) = o;
  }
}

// ---------------- kernel 2: prep (cast W, cast A, build gB, zero xa pad) ----
__global__ void prep_kernel(const float* __restrict__ W,
                            const float* __restrict__ A_all,
                            const float* __restrict__ B_all,
                            const int* __restrict__ idx,
                            const float* __restrict__ gates,
                            unsigned short* __restrict__ wbf,
                            unsigned short* __restrict__ abf,
                            unsigned short* __restrict__ gbbf,
                            unsigned short* __restrict__ xabf) {
  const int W_UNITS = 131072;                 // 8 elems each (1M total)
  const int A_UNITS = 16384;                  // 8 elems each (131072 total)
  const int G_UNITS = 65536;                  // one (b,n) row of 32 each
  const int P_UNITS = 6144;                   // xa pad elems (192 rows * 32)
  const int TOTAL = W_UNITS + A_UNITS + G_UNITS + P_UNITS;
  int u = blockIdx.x * blockDim.x + threadIdx.x;
  int stride = gridDim.x * blockDim.x;
  for (; u < TOTAL; u += stride) {
    if (u < W_UNITS) {
      int i = u * 8;
      *(bf16x8*)(wbf + i) = cvt8(W + i);
    } else if (u < W_UNITS + A_UNITS) {
      int i = (u - W_UNITS) * 8;
      *(bf16x8*)(abf + i) = cvt8(A_all + i);
    } else if (u < W_UNITS + A_UNITS + G_UNITS) {
      int v = u - W_UNITS - A_UNITS;
      int b = v >> 10;
      int n = v & 1023;
      unsigned short tmp[32];
#pragma unroll
      for (int k = 0; k < 2; ++k) {
        int e = idx[b * 2 + k];
        float g = gates[b * 2 + k];
        const float* Br = B_all + ((size_t)e * 1024 + n) * 16;
#pragma unroll
        for (int r = 0; r < 16; ++r) tmp[k * 16 + r] = f2bf(g * Br[r]);
      }
      unsigned short* dst = gbbf + (size_t)v * 32;
#pragma unroll
      for (int j = 0; j < 32; ++j) dst[j] = tmp[j];
    } else {
      int v = u - W_UNITS - A_UNITS - G_UNITS;
      xabf[(size_t)M_REAL * 32 + v] = 0;
    }
  }
}

// ---------------- kernel 3: xa = x @ A_sel^T  (per-b MFMA GEMM) -------------
__global__ __launch_bounds__(256) void xa_kernel(
    const unsigned short* __restrict__ xbf,
    const unsigned short* __restrict__ abf,
    const int* __restrict__ idx,
    unsigned short* __restrict__ xabf) {
  int bid = blockIdx.x;
  int b = bid / 10;
  int s0 = (bid % 10) * 64;
  int wave = threadIdx.x >> 6;
  int lane = threadIdx.x & 63;
  int l15 = lane & 15, lhi = lane >> 4;

  int srow = s0 + wave * 16 + l15;
  long long mrow = (long long)b * SSEQ + srow;     // < M_PAD
  const unsigned short* xrow = xbf + (size_t)mrow * DDIM;
  int e0 = idx[b * 2 + 0], e1 = idx[b * 2 + 1];
  const unsigned short* ar0 = abf + ((size_t)e0 * 16 + l15) * DDIM;
  const unsigned short* ar1 = abf + ((size_t)e1 * 16 + l15) * DDIM;

  f32x4 acc0 = {0.f, 0.f, 0.f, 0.f}, acc1 = {0.f, 0.f, 0.f, 0.f};
  for (int k = 0; k < DDIM; k += 32) {
    int ko = k + lhi * 8;
    bf16x8 a  = *(const bf16x8*)(xrow + ko);
    bf16x8 b0 = *(const bf16x8*)(ar0 + ko);
    bf16x8 b1 = *(const bf16x8*)(ar1 + ko);
    acc0 = __builtin_amdgcn_mfma_f32_16x16x32_bf16(a, b0, acc0, 0, 0, 0);
    acc1 = __builtin_amdgcn_mfma_f32_16x16x32_bf16(a, b1, acc1, 0, 0, 0);
  }
  int sout = s0 + wave * 16 + lhi * 4;
#pragma unroll
  for (int reg = 0; reg < 4; ++reg) {
    int s = sout + reg;
    if (s < SSEQ) {
      size_t mo = ((size_t)b * SSEQ + s) * 32;
      xabf[mo + l15]      = f2bf(acc0[reg]);
      xabf[mo + 16 + l15] = f2bf(acc1[reg]);
    }
  }
}

// ---------------- kernel 4: 256x256 8-wave counted-vmcnt GEMM + LoRA + bias -
// C[m,n] = sum_d x[m,d]*W[n,d] + bias[n] + sum_kr xa[m,kr]*gB[b(m),n,kr]
// LDS swizzle: LDS[row][chunk q] = global[row][q ^ (row&7)]  (16B chunks)
__global__ __launch_bounds__(512, 2) void gemm_kernel(
    const unsigned short* __restrict__ xbf,
    const unsigned short* __restrict__ wbf,
    const unsigned short* __restrict__ xabf,
    const unsigned short* __restrict__ gbbf,
    const float* __restrict__ bias,
    float* __restrict__ out) {
  __shared__ unsigned short Abuf[2][16384];   // 256x64 bf16 each
  __shared__ unsigned short Bbuf[2][16384];

  // m204 bijective XCD-chunked swizzle: NWG=580 = 8*72 + 4
  int g = blockIdx.x;
  int xcd = g & 7, gi = g >> 3;
  int wg = (xcd < 4 ? xcd * 73 : 292 + (xcd - 4) * 72) + gi;
  const int bm = wg >> 2;                    // 0..144
  const int bn = wg & 3;                     // 0..3
  const long long m0 = (long long)bm * 256;
  const int n0 = bn * 256;
  const int tid = threadIdx.x;
  const int lane = tid & 63;
  const int wave = tid >> 6;
  const int l15 = lane & 15, lhi = lane >> 4;
  const int wmi = wave >> 2;                 // 0..1  (128-row half)
  const int wni = wave & 3;                  // 0..3  (64-col quarter)

  // ---- staging constants (global source pre-swizzled; LDS dest linear) ----
  const int rstage = tid >> 3;                                      // 0..63
  const int csrc = (((tid & 7) ^ (rstage & 7)) << 3);               // elems
  const unsigned short* gAp = xbf + (size_t)(m0 + rstage) * DDIM + csrc;
  const unsigned short* gBp = wbf + (size_t)(n0 + rstage) * DDIM + csrc;
  const int ldsbase = wave * 512;            // elems; wave-uniform, HW adds lane*16B

  // ---- fragment-read constants (swizzled ds_read addresses) ----
  // desired global chunk (ks*4 + lhi); read LDS chunk = desired ^ (row&7), row&7 = l15&7
  const int sl0 = ((lhi ^ (l15 & 7)) << 3);  // elems, ks=0
  const int sl1 = sl0 ^ 32;                  // elems, ks=1 (XOR the ks bit!)
  const int rowA0 = (wmi * 128 + l15) * 64;
  const int rowB0 = (wni * 64 + l15) * 64;

  f32x4 acc[8][4];
#pragma unroll
  for (int i = 0; i < 8; ++i)
#pragma unroll
    for (int j = 0; j < 4; ++j) acc[i][j] = (f32x4){0.f, 0.f, 0.f, 0.f};

  // ---- prologue: stage tiles 0 and 1 ----
#pragma unroll
  for (int l = 0; l < 4; ++l) {
    GLOAD_LDS16(gAp + (size_t)l * 64 * DDIM, &Abuf[0][l * 4096 + ldsbase]);
    GLOAD_LDS16(gBp + (size_t)l * 64 * DDIM, &Bbuf[0][l * 4096 + ldsbase]);
  }
#pragma unroll
  for (int l = 0; l < 4; ++l) {
    GLOAD_LDS16(gAp + (size_t)l * 64 * DDIM + 64, &Abuf[1][l * 4096 + ldsbase]);
    GLOAD_LDS16(gBp + (size_t)l * 64 * DDIM + 64, &Bbuf[1][l * 4096 + ldsbase]);
  }
  asm volatile("s_waitcnt vmcnt(8)" ::: "memory");   // tile 0 landed (mine)
  __builtin_amdgcn_s_barrier();                      // everyone's tile 0 landed
  asm volatile("" ::: "memory");

  for (int t = 0; t < NT; ++t) {
    const unsigned short* As = Abuf[t & 1];
    const unsigned short* Bs = Bbuf[t & 1];

    // B fragments for the whole tile (4 n-frags x 2 k-steps)
    bf16x8 bfr[4][2];
#pragma unroll
    for (int nf = 0; nf < 4; ++nf) {
      bfr[nf][0] = *(const bf16x8*)&Bs[rowB0 + nf * 1024 + sl0];
      bfr[nf][1] = *(const bf16x8*)&Bs[rowB0 + nf * 1024 + sl1];
    }

#pragma unroll
    for (int mh = 0; mh < 2; ++mh) {
      bf16x8 afr[4][2];
#pragma unroll
      for (int f = 0; f < 4; ++f) {
        afr[f][0] = *(const bf16x8*)&As[rowA0 + (mh * 64 + f * 16) * 64 + sl0];
        afr[f][1] = *(const bf16x8*)&As[rowA0 + (mh * 64 + f * 16) * 64 + sl1];
      }
      __builtin_amdgcn_s_setprio(1);
#pragma unroll
      for (int f = 0; f < 4; ++f)
#pragma unroll
        for (int nf = 0; nf < 4; ++nf)
#pragma unroll
          for (int ks = 0; ks < 2; ++ks)
            acc[mh * 4 + f][nf] = __builtin_amdgcn_mfma_f32_16x16x32_bf16(
                afr[f][ks], bfr[nf][ks], acc[mh * 4 + f][nf], 0, 0, 0);
      __builtin_amdgcn_s_setprio(0);
    }

    asm volatile("s_waitcnt lgkmcnt(0)" ::: "memory");
    __builtin_amdgcn_s_barrier();                    // B1: all waves done reading buf
    asm volatile("" ::: "memory");

    if (t + 2 < NT) {
      const size_t koff = (size_t)(t + 2) * 64;
#pragma unroll
      for (int l = 0; l < 4; ++l) {
        GLOAD_LDS16(gAp + (size_t)l * 64 * DDIM + koff, &Abuf[t & 1][l * 4096 + ldsbase]);
        GLOAD_LDS16(gBp + (size_t)l * 64 * DDIM + koff, &Bbuf[t & 1][l * 4096 + ldsbase]);
      }
      asm volatile("s_waitcnt vmcnt(8)" ::: "memory");  // tile t+1 landed (mine)
    } else {
      asm volatile("s_waitcnt vmcnt(0)" ::: "memory");  // drain tail (t=14,15 only)
    }
    __builtin_amdgcn_s_barrier();                    // B2: everyone's tile t+1 landed
    asm volatile("" ::: "memory");
  }

  // ---- LoRA rank-32 extra K-steps, masked per batch (tile spans <= 2) ----
  long long mlast = m0 + 255; if (mlast > M_REAL - 1) mlast = M_REAL - 1;
  int b_lo = (int)(m0 / SSEQ);
  int b_hi = (int)(mlast / SSEQ);
  for (int bs = b_lo; bs <= b_hi; ++bs) {
    bf16x8 gb[4];
#pragma unroll
    for (int nf = 0; nf < 4; ++nf) {
      int n = n0 + wni * 64 + nf * 16 + l15;
      gb[nf] = *(const bf16x8*)&gbbf[((size_t)bs * 1024 + n) * 32 + lhi * 8];
    }
#pragma unroll
    for (int f8 = 0; f8 < 8; ++f8) {
      long long m = m0 + wmi * 128 + f8 * 16 + l15;
      bf16x8 av = *(const bf16x8*)&xabf[(size_t)m * 32 + lhi * 8];  // pad rows zero
      if ((int)(m / SSEQ) != bs) {
#pragma unroll
        for (int j = 0; j < 8; ++j) av[j] = 0;
      }
#pragma unroll
      for (int nf = 0; nf < 4; ++nf)
        acc[f8][nf] = __builtin_amdgcn_mfma_f32_16x16x32_bf16(av, gb[nf], acc[f8][nf], 0, 0, 0);
    }
  }

  // ---- epilogue: + bias, store fp32 ----
  float bv[4];
#pragma unroll
  for (int nf = 0; nf < 4; ++nf) bv[nf] = bias[n0 + wni * 64 + nf * 16 + l15];
#pragma unroll
  for (int f8 = 0; f8 < 8; ++f8) {
#pragma unroll
    for (int nf = 0; nf < 4; ++nf) {
      int n = n0 + wni * 64 + nf * 16 + l15;
#pragma unroll
      for (int r = 0; r < 4; ++r) {
        long long m = m0 + wmi * 128 + f8 * 16 + lhi * 4 + r;
        if (m < M_REAL) out[m * DDIM + n] = acc[f8][nf][r] + bv[nf];
      }
    }
  }
}

extern "C" void kernel_launch(void* const* d_in, const int* in_sizes, int n_in,
                              void* d_out, int out_size, void* d_ws, size_t ws_size,
                              hipStream_t stream) {
  const float* x      = (const float*)d_in[0];
  const int*   idx    = (const int*)d_in[1];
  const float* gates  = (const float*)d_in[2];
  const float* W      = (const float*)d_in[3];
  const float* A_all  = (const float*)d_in[4];
  const float* B_all  = (const float*)d_in[5];
  const float* bias   = (const float*)d_in[6];
  float* out = (float*)d_out;

  char* ws = (char*)d_ws;
  unsigned short* xbf  = (unsigned short*)(ws + XBF_OFF);
  unsigned short* wbf  = (unsigned short*)(ws + WBF_OFF);
  unsigned short* abf  = (unsigned short*)(ws + ABF_OFF);
  unsigned short* xabf = (unsigned short*)(ws + XABF_OFF);
  unsigned short* gbbf = (unsigned short*)(ws + GBBF_OFF);

  cast_x_kernel<<<dim3(2048), dim3(256), 0, stream>>>(x, xbf);
  prep_kernel<<<dim3(840), dim3(256), 0, stream>>>(W, A_all, B_all, idx, gates,
                                                   wbf, abf, gbbf, xabf);
  xa_kernel<<<dim3(640), dim3(256), 0, stream>>>(xbf, abf, idx, xabf);
  gemm_kernel<<<dim3(580), dim3(512), 0, stream>>>(xbf, wbf, xabf, gbbf, bias, out);
}